// Round 3
// baseline (100.760 us; speedup 1.0000x reference)
//
#include <hip/hip_runtime.h>
#include <math.h>

// Chamfer loss, B=32, N=2048, 3 used components.
// R4 (resubmit; round 2 bench was a GPU-acquisition timeout, no data):
// R2's geometry (high occupancy) + R3's atomic-free epilogues.
// Grid (16,8,32) = 4096 blocks, 256 thr; block = 128 rows x 256 cols tile;
// thread = 8 rows x 16 cols. Staged q' = {-2x,-2y,-2z,|q|^2}, p in regs:
//   dot' = p.q'(xyz); row min(dot'+y2); col min(dot'+x2); 6 VALU/pair.
// Row/col minima written as NON-ATOMIC partials (x2/y2 pre-added; min
// commutes): ws_row[b][bi][bj][128] (2 MiB), ws_col[b][bj][bi][256] (4 MiB),
// both coalesced via LDS funnels. Finish kernel min-reduces partials,
// sqrt+sum, 256 same-address atomicAdds. No sentinel memset, no atomicMin.

#define NPTS   2048
#define NBATCH 32
#define NBI    16                      // row chunks of 128
#define NBJ    8                       // col chunks of 256
#define WS_ROW_FLOATS ((size_t)NBATCH * NBI * NBJ * 128)   // 524288 = 2 MiB
#define EPSF   1e-16f
#define BIGF   3.4e38f

__device__ __forceinline__ float min3f(float a, float b, float c) {
    return fminf(fminf(a, b), c);      // -> v_min3_f32
}

__global__ __launch_bounds__(256) void chamfer_tile_kernel(
    const float* __restrict__ P, const float* __restrict__ Q,
    float* __restrict__ ws)
{
    __shared__ float4 sq[256];         // {-2x,-2y,-2z,|q|^2}
    __shared__ float  scol[4][256];    // per-wave col partials
    __shared__ float  rrow[128];       // row-min funnel (coalesced write-out)

    const int tid  = threadIdx.x;
    const int tx   = tid & 15;         // col group
    const int ty   = tid >> 4;         // row group 0..15
    const int lane = tid & 63;
    const int wv   = tid >> 6;
    const int bi   = blockIdx.x;       // row chunk (p)
    const int bj   = blockIdx.y;       // col chunk (q)
    const int b    = blockIdx.z;       // batch

    // ---- stage q tile (1 float4 load, coalesced)
    {
        float4 qv = ((const float4*)Q)[(size_t)b * NPTS + bj * 256 + tid];
        sq[tid] = make_float4(-2.f * qv.y, -2.f * qv.z, -2.f * qv.w,
                              qv.y * qv.y + qv.z * qv.z + qv.w * qv.w);
    }

    // ---- thread's 8 p rows: r = ty + 16k (4 distinct lines/wave -> L1)
    const float4* Pb = (const float4*)P + (size_t)b * NPTS + (size_t)bi * 128;
    float px[8], py[8], pz[8], x2[8], rowacc[8];
    #pragma unroll
    for (int k = 0; k < 8; ++k) {
        float4 v = Pb[ty + 16 * k];
        px[k] = v.y; py[k] = v.z; pz[k] = v.w;
        x2[k] = v.y * v.y + v.z * v.z + v.w * v.w;
        rowacc[k] = BIGF;
    }
    __syncthreads();

    // ---- main loop: thread's 16 cols c = tx + 16j, pairs j0=2jp, j1=2jp+1
    float colacc[16];
    #pragma unroll
    for (int jp = 0; jp < 8; ++jp) {
        float4 q0 = sq[tx + 32 * jp];
        float4 q1 = sq[tx + 32 * jp + 16];
        float c0 = BIGF, c1 = BIGF;
        #pragma unroll
        for (int k = 0; k < 8; k += 2) {
            float t00 = fmaf(px[k],   q0.x, fmaf(py[k],   q0.y, pz[k]   * q0.z));
            float t01 = fmaf(px[k],   q1.x, fmaf(py[k],   q1.y, pz[k]   * q1.z));
            float t10 = fmaf(px[k+1], q0.x, fmaf(py[k+1], q0.y, pz[k+1] * q0.z));
            float t11 = fmaf(px[k+1], q1.x, fmaf(py[k+1], q1.y, pz[k+1] * q1.z));
            rowacc[k]   = min3f(rowacc[k],   t00 + q0.w, t01 + q1.w);
            rowacc[k+1] = min3f(rowacc[k+1], t10 + q0.w, t11 + q1.w);
            c0 = min3f(c0, t00 + x2[k], t10 + x2[k+1]);
            c1 = min3f(c1, t01 + x2[k], t11 + x2[k+1]);
        }
        colacc[2*jp]     = c0;
        colacc[2*jp + 1] = c1;
    }

    // ---- row epilogue: reduce over tx (lane bits 0..3) -> rrow funnel
    #pragma unroll
    for (int k = 0; k < 8; ++k) {
        float v = rowacc[k];
        v = fminf(v, __shfl_xor(v, 1));
        v = fminf(v, __shfl_xor(v, 2));
        v = fminf(v, __shfl_xor(v, 4));
        v = fminf(v, __shfl_xor(v, 8));
        if (tx == 0) rrow[ty + 16 * k] = x2[k] + v;   // fold x2 (min commutes)
    }

    // ---- col epilogue: in-wave reduce over ty (lane bits 4,5), publish
    #pragma unroll
    for (int j = 0; j < 16; ++j) {
        float v = colacc[j];
        v = fminf(v, __shfl_xor(v, 16));
        v = fminf(v, __shfl_xor(v, 32));
        colacc[j] = v;
    }
    if (lane < 16) {                   // lane == tx representative
        #pragma unroll
        for (int j = 0; j < 16; ++j) scol[wv][j * 16 + lane] = colacc[j];
    }
    __syncthreads();

    // ---- coalesced global writes of partials
    {   // col partial: min over 4 waves, fold y2
        float v = fminf(fminf(scol[0][tid], scol[1][tid]),
                        fminf(scol[2][tid], scol[3][tid]));
        float* wsC = ws + WS_ROW_FLOATS;
        wsC[(((size_t)b * NBJ + bj) * NBI + bi) * 256 + tid] = v + sq[tid].w;
    }
    if (tid < 128) {                   // row partial
        ws[(((size_t)b * NBI + bi) * NBJ + bj) * 128 + tid] = rrow[tid];
    }
}

__global__ __launch_bounds__(256) void chamfer_finish_kernel(
    const float* __restrict__ ws, float* __restrict__ out)
{
    __shared__ float rbuf[4];
    const int tid = threadIdx.x;
    const int i   = blockIdx.x * 256 + tid;   // 0..65535
    const int b   = i >> 11;
    const int e   = i & 2047;

    // row side: min over 8 bj partials (coalesced: consecutive tid -> rl)
    float s;
    {
        const int bi = e >> 7, rl = e & 127;
        const float* rb = ws + ((size_t)(b * NBI + bi) * NBJ) * 128 + rl;
        float v = BIGF;
        #pragma unroll
        for (int j = 0; j < NBJ; ++j) v = fminf(v, rb[j * 128]);
        s = sqrtf(fmaxf(v, 0.f) + EPSF);
    }
    // col side: min over 16 bi partials (coalesced: consecutive tid -> cl)
    {
        const int bj = e >> 8, cl = e & 255;
        const float* cb = ws + WS_ROW_FLOATS
                        + ((size_t)(b * NBJ + bj) * NBI) * 256 + cl;
        float v = BIGF;
        #pragma unroll
        for (int j = 0; j < NBI; ++j) v = fminf(v, cb[j * 256]);
        s += sqrtf(fmaxf(v, 0.f) + EPSF);
    }

    #pragma unroll
    for (int off = 32; off > 0; off >>= 1) s += __shfl_down(s, off);
    if ((tid & 63) == 0) rbuf[tid >> 6] = s;
    __syncthreads();
    if (tid == 0)
        atomicAdd(out, 0.5f * ((rbuf[0] + rbuf[1]) + (rbuf[2] + rbuf[3])));
}

extern "C" void kernel_launch(void* const* d_in, const int* in_sizes, int n_in,
                              void* d_out, int out_size, void* d_ws, size_t ws_size,
                              hipStream_t stream) {
    const float* P = (const float*)d_in[0];   // p[0] = first 32*2048*4 floats
    const float* Q = (const float*)d_in[1];
    float* out = (float*)d_out;
    float* ws  = (float*)d_ws;                // uses 6 MiB

    hipMemsetAsync(out, 0, sizeof(float), stream);
    dim3 grid(NBI, NBJ, NBATCH);              // 16 x 8 x 32 = 4096 blocks
    chamfer_tile_kernel<<<grid, 256, 0, stream>>>(P, Q, ws);
    chamfer_finish_kernel<<<256, 256, 0, stream>>>(ws, out);
}

// Round 5
// 95.541 us; speedup vs baseline: 1.0546x; 1.0546x over previous
//
#include <hip/hip_runtime.h>
#include <math.h>

// Chamfer loss, B=32, N=2048, 3 used components.
// R5 (resubmit; round 4 bench was a GPU-acquisition timeout, no data):
// pure-register main loop. Block = 128x128 tile, grid (16,16,32)=8192
// blocks, 256 thr; thread = 8 rows x 8 cols. q' = {-2x,-2y,-2z,|q|^2} staged
// through LDS ONCE then held in 8 float4 regs; p rows in regs. Main loop:
// 384 straight-line VALU, no LDS, no barriers (kills the DS-latency stalls
// behind R4's 55% VALUBusy). Per-pair math identical: dot' = p.q'(xyz);
// row min(dot'+y2); col min(dot'+x2); 6 VALU/pair.
// Epilogues: shuffle reduces -> LDS funnels -> NON-ATOMIC coalesced partials
// (x2/y2 folded): ws_row[b][bi][bj][128] 4MiB, ws_col[b][bj][bi][128] 4MiB.
// Finish kernel: min over 16 partials each side, sqrt, sum, 256 atomicAdds.

#define NPTS   2048
#define NBATCH 32
#define NBI    16                      // row chunks of 128
#define NBJ    16                      // col chunks of 128
#define WS_ROW_FLOATS ((size_t)NBATCH * NBI * NBJ * 128)   // 1M floats = 4 MiB
#define EPSF   1e-16f
#define BIGF   3.4e38f

__device__ __forceinline__ float min3f(float a, float b, float c) {
    return fminf(fminf(a, b), c);      // -> v_min3_f32
}

__global__ __launch_bounds__(256) void chamfer_tile_kernel(
    const float* __restrict__ P, const float* __restrict__ Q,
    float* __restrict__ ws)
{
    __shared__ float4 sq[128];         // {-2x,-2y,-2z,|q|^2}
    __shared__ float  scol[4][128];    // per-wave col partials
    __shared__ float  rrow[128];       // row-min funnel

    const int tid  = threadIdx.x;
    const int tx   = tid & 15;         // col group
    const int ty   = tid >> 4;         // row group 0..15
    const int lane = tid & 63;
    const int wv   = tid >> 6;
    const int bi   = blockIdx.x;       // row chunk (p)
    const int bj   = blockIdx.y;       // col chunk (q)
    const int b    = blockIdx.z;       // batch

    // ---- stage q tile to LDS (threads 0..127, coalesced float4)
    if (tid < 128) {
        float4 qv = ((const float4*)Q)[(size_t)b * NPTS + bj * 128 + tid];
        sq[tid] = make_float4(-2.f * qv.y, -2.f * qv.z, -2.f * qv.w,
                              qv.y * qv.y + qv.z * qv.z + qv.w * qv.w);
    }

    // ---- thread's 8 p rows: r = ty + 16k (L1 broadcast, 4 lines/wave)
    const float4* Pb = (const float4*)P + (size_t)b * NPTS + (size_t)bi * 128;
    float px[8], py[8], pz[8], x2[8], rowacc[8];
    #pragma unroll
    for (int k = 0; k < 8; ++k) {
        float4 v = Pb[ty + 16 * k];
        px[k] = v.y; py[k] = v.z; pz[k] = v.w;
        x2[k] = v.y * v.y + v.z * v.z + v.w * v.w;
        rowacc[k] = BIGF;
    }
    __syncthreads();

    // ---- thread's 8 q cols c = tx + 16j -> registers (one-time LDS read)
    float4 qr[8];
    #pragma unroll
    for (int j = 0; j < 8; ++j) qr[j] = sq[tx + 16 * j];

    // ---- main loop: PURE REGISTER. 4 jp x 4 k-quads x 24 VALU = 384 VALU.
    float colacc[8];
    #pragma unroll
    for (int jp = 0; jp < 4; ++jp) {
        float4 q0 = qr[2 * jp];
        float4 q1 = qr[2 * jp + 1];
        float c0 = BIGF, c1 = BIGF;
        #pragma unroll
        for (int k = 0; k < 8; k += 2) {
            float t00 = fmaf(px[k],   q0.x, fmaf(py[k],   q0.y, pz[k]   * q0.z));
            float t01 = fmaf(px[k],   q1.x, fmaf(py[k],   q1.y, pz[k]   * q1.z));
            float t10 = fmaf(px[k+1], q0.x, fmaf(py[k+1], q0.y, pz[k+1] * q0.z));
            float t11 = fmaf(px[k+1], q1.x, fmaf(py[k+1], q1.y, pz[k+1] * q1.z));
            rowacc[k]   = min3f(rowacc[k],   t00 + q0.w, t01 + q1.w);
            rowacc[k+1] = min3f(rowacc[k+1], t10 + q0.w, t11 + q1.w);
            c0 = min3f(c0, t00 + x2[k], t10 + x2[k+1]);
            c1 = min3f(c1, t01 + x2[k], t11 + x2[k+1]);
        }
        colacc[2*jp]     = c0;
        colacc[2*jp + 1] = c1;
    }

    // ---- row epilogue: reduce over tx (lane bits 0..3) -> rrow funnel
    #pragma unroll
    for (int k = 0; k < 8; ++k) {
        float v = rowacc[k];
        v = fminf(v, __shfl_xor(v, 1));
        v = fminf(v, __shfl_xor(v, 2));
        v = fminf(v, __shfl_xor(v, 4));
        v = fminf(v, __shfl_xor(v, 8));
        if (tx == 0) rrow[ty + 16 * k] = x2[k] + v;   // fold x2 (min commutes)
    }

    // ---- col epilogue: in-wave reduce over ty (lane bits 4,5), publish
    #pragma unroll
    for (int j = 0; j < 8; ++j) {
        float v = colacc[j];
        v = fminf(v, __shfl_xor(v, 16));
        v = fminf(v, __shfl_xor(v, 32));
        colacc[j] = v;
    }
    if (lane < 16) {                   // lane == tx representative
        #pragma unroll
        for (int j = 0; j < 8; ++j) scol[wv][j * 16 + lane] = colacc[j];
    }
    __syncthreads();

    // ---- coalesced global writes of partials (threads 0..127)
    if (tid < 128) {
        float v = fminf(fminf(scol[0][tid], scol[1][tid]),
                        fminf(scol[2][tid], scol[3][tid]));
        float* wsC = ws + WS_ROW_FLOATS;
        wsC[(((size_t)b * NBJ + bj) * NBI + bi) * 128 + tid] = v + sq[tid].w;
        ws[(((size_t)b * NBI + bi) * NBJ + bj) * 128 + tid] = rrow[tid];
    }
}

__global__ __launch_bounds__(256) void chamfer_finish_kernel(
    const float* __restrict__ ws, float* __restrict__ out)
{
    __shared__ float rbuf[4];
    const int tid = threadIdx.x;
    const int i   = blockIdx.x * 256 + tid;   // 0..65535
    const int b   = i >> 11;
    const int e   = i & 2047;
    const int ch  = e >> 7;                    // chunk index 0..15
    const int el  = e & 127;                   // element in chunk

    // row side: min over 16 bj partials (coalesced in el)
    float s;
    {
        const float* rb = ws + ((size_t)(b * NBI + ch) * NBJ) * 128 + el;
        float v = BIGF;
        #pragma unroll
        for (int j = 0; j < NBJ; ++j) v = fminf(v, rb[j * 128]);
        s = sqrtf(fmaxf(v, 0.f) + EPSF);
    }
    // col side: min over 16 bi partials (coalesced in el)
    {
        const float* cb = ws + WS_ROW_FLOATS
                        + ((size_t)(b * NBJ + ch) * NBI) * 128 + el;
        float v = BIGF;
        #pragma unroll
        for (int j = 0; j < NBI; ++j) v = fminf(v, cb[j * 128]);
        s += sqrtf(fmaxf(v, 0.f) + EPSF);
    }

    #pragma unroll
    for (int off = 32; off > 0; off >>= 1) s += __shfl_down(s, off);
    if ((tid & 63) == 0) rbuf[tid >> 6] = s;
    __syncthreads();
    if (tid == 0)
        atomicAdd(out, 0.5f * ((rbuf[0] + rbuf[1]) + (rbuf[2] + rbuf[3])));
}

extern "C" void kernel_launch(void* const* d_in, const int* in_sizes, int n_in,
                              void* d_out, int out_size, void* d_ws, size_t ws_size,
                              hipStream_t stream) {
    const float* P = (const float*)d_in[0];   // p[0] = first 32*2048*4 floats
    const float* Q = (const float*)d_in[1];
    float* out = (float*)d_out;
    float* ws  = (float*)d_ws;                // uses 8 MiB

    hipMemsetAsync(out, 0, sizeof(float), stream);
    dim3 grid(NBI, NBJ, NBATCH);              // 16 x 16 x 32 = 8192 blocks
    chamfer_tile_kernel<<<grid, 256, 0, stream>>>(P, Q, ws);
    chamfer_finish_kernel<<<256, 256, 0, stream>>>(ws, out);
}

// Round 6
// 91.186 us; speedup vs baseline: 1.1050x; 1.0478x over previous
//
#include <hip/hip_runtime.h>
#include <math.h>

// Chamfer loss, B=32, N=2048, 3 used components.
// R6: persistent-column blocks. Grid (16 bj, 2 half, 32 b) = 1024 blocks of
// 256 thr = exactly 4 blocks/CU resident (16 waves/CU, launch_bounds(256,4)).
// Block holds 128 q-cols in REGISTERS (q' = {-2x,-2y,-2z,|q|^2}, staged via
// LDS once); loops over 8 row-chunks of 128: 8 coalesced p-loads -> pure-reg
// compute -> shuffle row-reduce -> partial store. ZERO barriers in the loop.
// Instruction cut: fold x2 into innermost fma (t = dot' + x2, 3 fma), defer
// y2: row d2 = t + y2 (1 add), col partial = min_k t (no add) -> 5 VALU/pair
// (20 per 2x2 quad) vs 6 before. Col minima finish in-block (+y2 folded) ->
// ws_col[b][bj][half][128] (512 KB); row partials ws_row[b][bi][bj][128]
// (4 MiB), finish kernel min-reduces 16 bj / 2 halves, sqrt, sum, atomicAdd.

#define NPTS   2048
#define NBATCH 32
#define NBI    16                      // row chunks of 128 (global index)
#define NBJ    16                      // col chunks of 128
#define NHALF  2                       // row halves per (b,bj) block pair
#define WS_ROW_FLOATS ((size_t)NBATCH * NBI * NBJ * 128)   // 1M floats = 4 MiB
#define EPSF   1e-16f
#define BIGF   3.4e38f

__device__ __forceinline__ float min3f(float a, float b, float c) {
    return fminf(fminf(a, b), c);      // -> v_min3_f32
}

__global__ __launch_bounds__(256, 4) void chamfer_tile_kernel(
    const float* __restrict__ P, const float* __restrict__ Q,
    float* __restrict__ ws)
{
    __shared__ float4 sq[128];         // {-2x,-2y,-2z,|q|^2}
    __shared__ float  scol[4][128];    // per-wave col partials

    const int tid  = threadIdx.x;
    const int tx   = tid & 15;         // col group
    const int ty   = tid >> 4;         // row group 0..15
    const int lane = tid & 63;
    const int wv   = tid >> 6;
    const int bj   = blockIdx.x;       // col chunk (q)
    const int half = blockIdx.y;       // row half (0: rows 0..1023, 1: rest)
    const int b    = blockIdx.z;       // batch

    // ---- stage q tile to LDS once (threads 0..127, coalesced float4)
    if (tid < 128) {
        float4 qv = ((const float4*)Q)[(size_t)b * NPTS + bj * 128 + tid];
        sq[tid] = make_float4(-2.f * qv.y, -2.f * qv.z, -2.f * qv.w,
                              qv.y * qv.y + qv.z * qv.z + qv.w * qv.w);
    }
    __syncthreads();

    // ---- thread's 8 q cols c = tx + 16j -> unpacked registers
    float qx[8], qy[8], qz[8], qw[8], colacc[8];
    #pragma unroll
    for (int j = 0; j < 8; ++j) {
        float4 t = sq[tx + 16 * j];
        qx[j] = t.x; qy[j] = t.y; qz[j] = t.z; qw[j] = t.w;
        colacc[j] = BIGF;
    }

    const float4* Pb = (const float4*)P + (size_t)b * NPTS
                     + (size_t)half * (NPTS / 2);

    // ---- persistent loop over this half's 8 row chunks (NO barriers)
    for (int it = 0; it < 8; ++it) {
        const int bi = half * 8 + it;

        // 8 p rows r = ty + 16k (coalesced-ish, L1/L2 broadcast)
        float px[8], py[8], pz[8], x2[8], rowacc[8];
        #pragma unroll
        for (int k = 0; k < 8; ++k) {
            float4 v = Pb[it * 128 + ty + 16 * k];
            px[k] = v.y; py[k] = v.z; pz[k] = v.w;
            x2[k] = fmaf(v.y, v.y, fmaf(v.z, v.z, v.w * v.w));
            rowacc[k] = BIGF;
        }

        // pure-register compute: 4 jp x 4 k-quads x 20 VALU = 320 (5/pair)
        #pragma unroll
        for (int jp = 0; jp < 4; ++jp) {
            const int j0 = 2 * jp, j1 = 2 * jp + 1;
            #pragma unroll
            for (int k = 0; k < 8; k += 2) {
                // t = dot' + x2  (x2 folded into innermost fma)
                float t00 = fmaf(px[k],   qx[j0], fmaf(py[k],   qy[j0], fmaf(pz[k],   qz[j0], x2[k])));
                float t01 = fmaf(px[k],   qx[j1], fmaf(py[k],   qy[j1], fmaf(pz[k],   qz[j1], x2[k])));
                float t10 = fmaf(px[k+1], qx[j0], fmaf(py[k+1], qy[j0], fmaf(pz[k+1], qz[j0], x2[k+1])));
                float t11 = fmaf(px[k+1], qx[j1], fmaf(py[k+1], qy[j1], fmaf(pz[k+1], qz[j1], x2[k+1])));
                // col: min_k t (y2 deferred to epilogue)
                colacc[j0] = min3f(colacc[j0], t00, t10);
                colacc[j1] = min3f(colacc[j1], t01, t11);
                // row: d2 = t + y2
                rowacc[k]   = min3f(rowacc[k],   t00 + qw[j0], t01 + qw[j1]);
                rowacc[k+1] = min3f(rowacc[k+1], t10 + qw[j0], t11 + qw[j1]);
            }
        }

        // row reduce over tx (lane bits 0..3); rowacc IS d2 already
        #pragma unroll
        for (int k = 0; k < 8; ++k) {
            float v = rowacc[k];
            v = fminf(v, __shfl_xor(v, 1));
            v = fminf(v, __shfl_xor(v, 2));
            v = fminf(v, __shfl_xor(v, 4));
            v = fminf(v, __shfl_xor(v, 8));
            rowacc[k] = v;
        }
        if (tx == 0) {
            float* rb = ws + (((size_t)b * NBI + bi) * NBJ + bj) * 128;
            #pragma unroll
            for (int k = 0; k < 8; ++k) rb[ty + 16 * k] = rowacc[k];
        }
    }

    // ---- col epilogue: reduce over ty (lane bits 4,5), cross-wave via LDS
    #pragma unroll
    for (int j = 0; j < 8; ++j) {
        float v = colacc[j];
        v = fminf(v, __shfl_xor(v, 16));
        v = fminf(v, __shfl_xor(v, 32));
        colacc[j] = v;
    }
    if (lane < 16) {                   // lane == tx representative
        #pragma unroll
        for (int j = 0; j < 8; ++j) scol[wv][j * 16 + lane] = colacc[j];
    }
    __syncthreads();
    if (tid < 128) {
        float v = fminf(fminf(scol[0][tid], scol[1][tid]),
                        fminf(scol[2][tid], scol[3][tid]));
        float* cb = ws + WS_ROW_FLOATS
                  + (((size_t)b * NBJ + bj) * NHALF + half) * 128;
        cb[tid] = v + sq[tid].w;       // fold y2 (min over halves commutes)
    }
}

__global__ __launch_bounds__(256) void chamfer_finish_kernel(
    const float* __restrict__ ws, float* __restrict__ out)
{
    __shared__ float rbuf[4];
    const int tid = threadIdx.x;
    const int i   = blockIdx.x * 256 + tid;   // 0..65535
    const int b   = i >> 11;
    const int e   = i & 2047;
    const int ch  = e >> 7;                    // chunk index 0..15
    const int el  = e & 127;                   // element in chunk

    // row side: min over 16 bj partials (coalesced in el)
    float s;
    {
        const float* rb = ws + ((size_t)(b * NBI + ch) * NBJ) * 128 + el;
        float v = BIGF;
        #pragma unroll
        for (int j = 0; j < NBJ; ++j) v = fminf(v, rb[j * 128]);
        s = sqrtf(fmaxf(v, 0.f) + EPSF);
    }
    // col side: min over 2 half partials (coalesced in el)
    {
        const float* cb = ws + WS_ROW_FLOATS
                        + ((size_t)(b * NBJ + ch) * NHALF) * 128 + el;
        float v = fminf(cb[0], cb[128]);
        s += sqrtf(fmaxf(v, 0.f) + EPSF);
    }

    #pragma unroll
    for (int off = 32; off > 0; off >>= 1) s += __shfl_down(s, off);
    if ((tid & 63) == 0) rbuf[tid >> 6] = s;
    __syncthreads();
    if (tid == 0)
        atomicAdd(out, 0.5f * ((rbuf[0] + rbuf[1]) + (rbuf[2] + rbuf[3])));
}

extern "C" void kernel_launch(void* const* d_in, const int* in_sizes, int n_in,
                              void* d_out, int out_size, void* d_ws, size_t ws_size,
                              hipStream_t stream) {
    const float* P = (const float*)d_in[0];   // p[0] = first 32*2048*4 floats
    const float* Q = (const float*)d_in[1];
    float* out = (float*)d_out;
    float* ws  = (float*)d_ws;                // uses 4.5 MiB

    hipMemsetAsync(out, 0, sizeof(float), stream);
    dim3 grid(NBJ, NHALF, NBATCH);            // 16 x 2 x 32 = 1024 blocks
    chamfer_tile_kernel<<<grid, 256, 0, stream>>>(P, Q, ws);
    chamfer_finish_kernel<<<256, 256, 0, stream>>>(ws, out);
}